// Round 7
// baseline (57.905 us; speedup 1.0000x reference)
//
#include <hip/hip_runtime.h>

typedef __attribute__((ext_vector_type(8))) short short8;
typedef __attribute__((ext_vector_type(4))) float f32x4;
typedef __attribute__((ext_vector_type(2))) unsigned int u32x2;
typedef __attribute__((ext_vector_type(4))) unsigned int u32x4;

#define DEV __device__ __forceinline__

// ---------------- workspace layout (bf16 element offsets) ----------------
// Q [B,H,S,D] (pre-scaled by 1/8*log2e); K [B,H,S,D]; V^T [B,H,D,S]; ctx [B,S,E]
#define QH_E 0L
#define KH_E 2359296L
#define VT_E 4718592L
#define CTX_E 7077888L

#define LOG2E 1.4426950408889634f

#define BARRIER() __builtin_amdgcn_s_barrier()
#define SCHED0() __builtin_amdgcn_sched_barrier(0)

DEV unsigned short f2bf(float f) {  // RNE fp32 -> bf16 bits (inputs finite)
  unsigned int x = __float_as_uint(f);
  x = (x + 0x7fffu + ((x >> 16) & 1u)) >> 16;
  return (unsigned short)x;
}

DEV unsigned int pk2(float a, float b) {  // packed bf16 pair (RNE)
  unsigned int r;
  asm("v_cvt_pk_bf16_f32 %0, %1, %2" : "=v"(r) : "v"(a), "v"(b));
  return r;
}

DEV void gl2lds16(const unsigned short* g, unsigned short* l) {
  __builtin_amdgcn_global_load_lds(
      (const __attribute__((address_space(1))) unsigned int*)g,
      (__attribute__((address_space(3))) unsigned int*)l, 16, 0, 0);
}

DEV f32x4 mfma16(short8 a, short8 b, f32x4 c) {
  return __builtin_amdgcn_mfma_f32_16x16x32_bf16(a, b, c, 0, 0, 0);
}

// ---------------- QKV GEMM core: C[128x64] = A[128xK] * W[64xK]^T ----------
DEV void gemm_qkv(const float* __restrict__ A, const float* __restrict__ W,
                  int m0, int n0, unsigned short* ldsA, unsigned short* ldsB,
                  f32x4 acc[4][2]) {
  const int tid = threadIdx.x;
  const int lane = tid & 63, wvv = tid >> 6;
  const int g = lane >> 4, qi = lane & 15;
  const int wr = wvv >> 1, wc = wvv & 1;
  const int c8 = tid & 7, rbase = tid >> 3;
  const int j8 = (c8 ^ (rbase & 7)) * 8;  // swizzled source column (elements)
  f32x4 ra[4][2];
  f32x4 rw[2][2][2];  // [set][it][half]
#pragma unroll
  for (int mi = 0; mi < 4; ++mi)
#pragma unroll
    for (int ni = 0; ni < 2; ++ni) {
      f32x4 z = {0.f, 0.f, 0.f, 0.f};
      acc[mi][ni] = z;
    }
#define QLA(kt) do {                                                          \
    const int k0_ = (kt) * 64;                                                \
    _Pragma("unroll")                                                         \
    for (int it = 0; it < 4; ++it) {                                          \
      const float* p = A + (long)(m0 + it * 32 + rbase) * 512 + k0_ + j8;     \
      ra[it][0] = *(const f32x4*)p;                                           \
      ra[it][1] = *(const f32x4*)(p + 4);                                     \
    }                                                                         \
  } while (0)
#define QLB(kt) do {                                                          \
    const int k0_ = (kt) * 64;                                                \
    _Pragma("unroll")                                                         \
    for (int it = 0; it < 2; ++it) {                                          \
      const float* p = W + (long)(n0 + it * 32 + rbase) * 512 + k0_ + j8;     \
      rw[(kt) & 1][it][0] = *(const f32x4*)p;                                 \
      rw[(kt) & 1][it][1] = *(const f32x4*)(p + 4);                           \
    }                                                                         \
  } while (0)
#define QWA(bi) do {                                                          \
    _Pragma("unroll")                                                         \
    for (int it = 0; it < 4; ++it) {                                          \
      u32x4 v_;                                                               \
      v_.x = pk2(ra[it][0].x, ra[it][0].y);                                   \
      v_.y = pk2(ra[it][0].z, ra[it][0].w);                                   \
      v_.z = pk2(ra[it][1].x, ra[it][1].y);                                   \
      v_.w = pk2(ra[it][1].z, ra[it][1].w);                                   \
      *(u32x4*)(ldsA + (bi) * 8192 + (it * 256 + tid) * 8) = v_;              \
    }                                                                         \
  } while (0)
#define QWB(bi) do {                                                          \
    _Pragma("unroll")                                                         \
    for (int it = 0; it < 2; ++it) {                                          \
      u32x4 v_;                                                               \
      v_.x = pk2(rw[(bi)][it][0].x, rw[(bi)][it][0].y);                       \
      v_.y = pk2(rw[(bi)][it][0].z, rw[(bi)][it][0].w);                       \
      v_.z = pk2(rw[(bi)][it][1].x, rw[(bi)][it][1].y);                       \
      v_.w = pk2(rw[(bi)][it][1].z, rw[(bi)][it][1].w);                       \
      *(u32x4*)(ldsB + (bi) * 4096 + (it * 256 + tid) * 8) = v_;              \
    }                                                                         \
  } while (0)
  QLA(0); QLB(0); QLB(1);
  QWA(0); QWB(0);
  QLA(1); QLB(2);
  asm volatile("s_waitcnt lgkmcnt(0)" ::: "memory");
  BARRIER();
  SCHED0();
#pragma unroll
  for (int kt = 0; kt < 8; ++kt) {
    const unsigned short* La = ldsA + (kt & 1) * 8192;
    const unsigned short* Lb = ldsB + (kt & 1) * 4096;
    __builtin_amdgcn_s_setprio(1);
#pragma unroll
    for (int kk = 0; kk < 2; ++kk) {
      short8 af[4], bfr[2];
#pragma unroll
      for (int mi = 0; mi < 4; ++mi) {
        int row = 64 * wr + 16 * mi + qi;
        int c16 = (4 * kk + g) ^ (qi & 7);
        af[mi] = *(const short8*)(La + row * 64 + c16 * 8);
      }
#pragma unroll
      for (int ni = 0; ni < 2; ++ni) {
        int row = 32 * wc + 16 * ni + qi;
        int c16 = (4 * kk + g) ^ (qi & 7);
        bfr[ni] = *(const short8*)(Lb + row * 64 + c16 * 8);
      }
#pragma unroll
      for (int mi = 0; mi < 4; ++mi)
#pragma unroll
        for (int ni = 0; ni < 2; ++ni)
          acc[mi][ni] = mfma16(af[mi], bfr[ni], acc[mi][ni]);
    }
    __builtin_amdgcn_s_setprio(0);
    SCHED0();  // keep staging (and its waits) after the MFMA cluster
    if (kt < 7) { QWA((kt + 1) & 1); QWB((kt + 1) & 1); }
    if (kt < 6) QLA(kt + 2);
    if (kt < 5) QLB(kt + 3);  // set (kt+3)&1 == (kt+1)&1, just consumed
    if (kt < 7) {
      asm volatile("s_waitcnt lgkmcnt(0)" ::: "memory");
      BARRIER();
      SCHED0();
    }
  }
#undef QLA
#undef QLB
#undef QWA
#undef QWB
}

// ---------------- out-proj GEMM core: C[64x64] = A[64xK]*W[64xK]^T ---------
DEV void gemm_o(const unsigned short* __restrict__ A, const float* __restrict__ W,
                int m0, int n0, unsigned short* ldsA, unsigned short* ldsB,
                f32x4 acc[2][2]) {
  const int tid = threadIdx.x;
  const int lane = tid & 63, wvv = tid >> 6;
  const int g = lane >> 4, qi = lane & 15;
  const int wr = wvv >> 1, wc = wvv & 1;
  const int c8 = tid & 7, rbase = tid >> 3;
  const int j8 = (c8 ^ (rbase & 7)) * 8;
  u32x4 rab[2][2];    // [set][it]
  f32x4 rw[2][2][2];  // [set][it][half]
#pragma unroll
  for (int mi = 0; mi < 2; ++mi)
#pragma unroll
    for (int ni = 0; ni < 2; ++ni) {
      f32x4 z = {0.f, 0.f, 0.f, 0.f};
      acc[mi][ni] = z;
    }
#define OLA(kt) do {                                                          \
    const int k0_ = (kt) * 64;                                                \
    _Pragma("unroll")                                                         \
    for (int it = 0; it < 2; ++it)                                            \
      rab[(kt) & 1][it] =                                                     \
          *(const u32x4*)(A + (long)(m0 + it * 32 + rbase) * 512 + k0_ + j8); \
  } while (0)
#define OLB(kt) do {                                                          \
    const int k0_ = (kt) * 64;                                                \
    _Pragma("unroll")                                                         \
    for (int it = 0; it < 2; ++it) {                                          \
      const float* p = W + (long)(n0 + it * 32 + rbase) * 512 + k0_ + j8;     \
      rw[(kt) & 1][it][0] = *(const f32x4*)p;                                 \
      rw[(kt) & 1][it][1] = *(const f32x4*)(p + 4);                           \
    }                                                                         \
  } while (0)
#define OW(kt) do {                                                           \
    const int b3_ = (kt) % 3, s_ = (kt) & 1;                                  \
    _Pragma("unroll")                                                         \
    for (int it = 0; it < 2; ++it)                                            \
      *(u32x4*)(ldsA + b3_ * 4096 + (it * 256 + tid) * 8) = rab[s_][it];      \
    _Pragma("unroll")                                                         \
    for (int it = 0; it < 2; ++it) {                                          \
      u32x4 v_;                                                               \
      v_.x = pk2(rw[s_][it][0].x, rw[s_][it][0].y);                           \
      v_.y = pk2(rw[s_][it][0].z, rw[s_][it][0].w);                           \
      v_.z = pk2(rw[s_][it][1].x, rw[s_][it][1].y);                           \
      v_.w = pk2(rw[s_][it][1].z, rw[s_][it][1].w);                           \
      *(u32x4*)(ldsB + b3_ * 4096 + (it * 256 + tid) * 8) = v_;               \
    }                                                                         \
  } while (0)
  OLA(0); OLB(0);
  OLA(1); OLB(1);
  OW(0);
  OLA(2); OLB(2);
  OW(1);
  OLA(3); OLB(3);
  asm volatile("s_waitcnt lgkmcnt(0)" ::: "memory");
  BARRIER();
  SCHED0();
#pragma unroll
  for (int kt = 0; kt < 8; ++kt) {
    const unsigned short* La = ldsA + (kt % 3) * 4096;
    const unsigned short* Lb = ldsB + (kt % 3) * 4096;
    __builtin_amdgcn_s_setprio(1);
#pragma unroll
    for (int kk = 0; kk < 2; ++kk) {
      short8 af[2], bfr[2];
#pragma unroll
      for (int mi = 0; mi < 2; ++mi) {
        int row = 32 * wr + 16 * mi + qi;
        int c16 = (4 * kk + g) ^ (qi & 7);
        af[mi] = *(const short8*)(La + row * 64 + c16 * 8);
      }
#pragma unroll
      for (int ni = 0; ni < 2; ++ni) {
        int row = 32 * wc + 16 * ni + qi;
        int c16 = (4 * kk + g) ^ (qi & 7);
        bfr[ni] = *(const short8*)(Lb + row * 64 + c16 * 8);
      }
#pragma unroll
      for (int mi = 0; mi < 2; ++mi)
#pragma unroll
        for (int ni = 0; ni < 2; ++ni)
          acc[mi][ni] = mfma16(af[mi], bfr[ni], acc[mi][ni]);
    }
    __builtin_amdgcn_s_setprio(0);
    SCHED0();
    if (kt < 6) OW(kt + 2);   // consumes loads issued 2 steps ago
    if (kt < 4) { OLA(kt + 4); OLB(kt + 4); }  // same set, just consumed
    if (kt < 7) {
      asm volatile("s_waitcnt lgkmcnt(0)" ::: "memory");
      BARRIER();
      SCHED0();
    }
  }
#undef OLA
#undef OLB
#undef OW
}

// ---------------- QKV projection (z: 0=Q,1=K,2=V), fused fp32 conversion ----
__global__ __launch_bounds__(256, 3) void proj_qkv_kernel(
    const float* __restrict__ xq, const float* __restrict__ xk,
    const float* __restrict__ xv, const float* __restrict__ wqp,
    const float* __restrict__ wkp, const float* __restrict__ wvp,
    const float* __restrict__ bq, const float* __restrict__ bk,
    const float* __restrict__ bv, unsigned short* __restrict__ ws) {
  __shared__ unsigned short ldsA[2 * 8192];
  __shared__ unsigned short ldsB[2 * 4096];
  int f = blockIdx.x;
  int wid = (f & 7) * 108 + (f >> 3);  // 864 = 8*108, bijective
  const int z = wid / 288;
  const int rem = wid % 288;
  const int m0 = (rem >> 3) * 128, n0 = (rem & 7) * 64;
  const float *A, *W, *bias;
  unsigned short* dst;
  float oscale;
  int mode;
  if (z == 0)      { A = xq; W = wqp; bias = bq; oscale = 0.125f * LOG2E; dst = ws + QH_E; mode = 0; }
  else if (z == 1) { A = xk; W = wkp; bias = bk; oscale = 1.0f;           dst = ws + KH_E; mode = 0; }
  else             { A = xv; W = wvp; bias = bv; oscale = 1.0f;           dst = ws + VT_E; mode = 1; }
  f32x4 acc[4][2];
  gemm_qkv(A, W, m0, n0, ldsA, ldsB, acc);
  const int lane = threadIdx.x & 63, wvv = threadIdx.x >> 6;
  const int g = lane >> 4, qi = lane & 15;
  const int wr = wvv >> 1, wc = wvv & 1;
#pragma unroll
  for (int ni = 0; ni < 2; ++ni) {
    int n = n0 + 32 * wc + 16 * ni + qi;
    float bb = bias[n];
    int h = n >> 6, d = n & 63;
#pragma unroll
    for (int mi = 0; mi < 4; ++mi) {
      int m = m0 + 64 * wr + 16 * mi + 4 * g;  // 4-aligned run stays in one batch
      int b = (m >= 2304) ? 1 : 0;
      int s = m - b * 2304;
      if (mode == 0) {
#pragma unroll
        for (int r = 0; r < 4; ++r) {
          float v = (acc[mi][ni][r] + bb) * oscale;
          dst[((long)((b * 8 + h) * 2304 + s + r)) * 64 + d] = f2bf(v);
        }
      } else {  // V^T: consecutive s -> packed 8B store
        u32x2 o;
        o.x = pk2(acc[mi][ni][0] + bb, acc[mi][ni][1] + bb);
        o.y = pk2(acc[mi][ni][2] + bb, acc[mi][ni][3] + bb);
        *(u32x2*)(dst + ((long)((b * 8 + h) * 64 + d)) * 2304 + s) = o;
      }
    }
  }
}

// ---------------- output projection: out = ctx @ Wo^T + bo (fp32 out) -------
__global__ __launch_bounds__(256, 3) void proj_out_kernel(
    const unsigned short* __restrict__ ws, const float* __restrict__ wop,
    const float* __restrict__ bo, float* __restrict__ out) {
  __shared__ unsigned short ldsA[3 * 4096];
  __shared__ unsigned short ldsB[3 * 4096];
  int f = blockIdx.x;
  int wid = (f & 7) * 72 + (f >> 3);  // 576 = 8*72, bijective
  const int m0 = (wid >> 3) * 64, n0 = (wid & 7) * 64;
  f32x4 acc[2][2];
  gemm_o(ws + CTX_E, wop, m0, n0, ldsA, ldsB, acc);
  const int lane = threadIdx.x & 63, wvv = threadIdx.x >> 6;
  const int g = lane >> 4, qi = lane & 15;
  const int wr = wvv >> 1, wc = wvv & 1;
#pragma unroll
  for (int ni = 0; ni < 2; ++ni) {
    int n = n0 + 32 * wc + 16 * ni + qi;
    float bb = bo[n];
#pragma unroll
    for (int mi = 0; mi < 2; ++mi) {
#pragma unroll
      for (int r = 0; r < 4; ++r) {
        int m = m0 + 32 * wr + 16 * mi + 4 * g + r;
        out[(long)m * 512 + n] = acc[mi][ni][r] + bb;
      }
    }
  }
}

// ---------------- windowed flash attention ----------------
// 2-deep chunk software pipeline: each iteration computes QK^T(t+1) (MFMA
// pipe, reads K(t+1) LDS) interleaved with softmax+PV(t) (VALU + LDS-roundtrip
// + MFMA, reads V(t) LDS). sacc double-buffered in registers (static parity).
// 3 KV buffers; {vmcnt(0) -> barrier -> stage(t+2)} per iteration.
__global__ __launch_bounds__(192) void attn_kernel(unsigned short* __restrict__ ws) {
  __shared__ unsigned short ldsKV[3 * 7168];   // per buf: K [48][64] | V^T [64][64]
  __shared__ unsigned short ldsP[3][16][72];   // per-wave P [16 q][64 k] (pad zeroed)
  __shared__ unsigned short ldsDum[512];       // dummy target for stage padding
  const int tid = threadIdx.x;
  const int lane = tid & 63, wv = tid >> 6;
  const int g = lane >> 4, qi = lane & 15;
  int f = blockIdx.x;
  int wid = (f & 7) * 96 + (f >> 3);           // 768 = 8*96, bijective
  const int bh = wid / 48, r = wid - 48 * bh;
  const int ci = wv * 16 + qi;                 // query col in grid row r
  const unsigned short* Kh = ws + KH_E + (long)bh * 2304 * 64;
  const unsigned short* Vt = ws + VT_E + (long)bh * 64 * 2304;
  const int q = r * 48 + ci;
  const unsigned short* qp = ws + QH_E + ((long)bh * 2304 + q) * 64;
  f32x4 qraw0 = *(const f32x4*)(qp + 8 * g);
  f32x4 qraw1 = *(const f32x4*)(qp + 32 + 8 * g);
  asm volatile("" : "+v"(qraw0), "+v"(qraw1));
  short8 qf0 = __builtin_bit_cast(short8, qraw0);
  short8 qf1 = __builtin_bit_cast(short8, qraw1);
  float msk[12];
#pragma unroll
  for (int mb = 0; mb < 3; ++mb)
#pragma unroll
    for (int rr = 0; rr < 4; ++rr) {
      int cj = 16 * mb + 4 * g + rr;
      msk[mb * 4 + rr] = ((unsigned)(ci - cj + 7) <= 14u) ? 0.f : -1e30f;
    }
  {  // zero the P pad (keys 48..63) once; wave-private
    u32x2 z2; z2.x = 0u; z2.y = 0u;
    *(u32x2*)(&ldsP[wv][qi][48 + 4 * g]) = z2;
  }
  f32x4 cacc[4];
#pragma unroll
  for (int mb = 0; mb < 4; ++mb) { f32x4 z = {0.f, 0.f, 0.f, 0.f}; cacc[mb] = z; }
  float lrun = 0.f;  // per-lane partial sum; reduced once at the end

#define ASTAGE(bi, rj) do {                                                   \
    unsigned short* Lb_ = ldsKV + (bi) * 7168;                                \
    const unsigned short* Ks_ = Kh + (long)(rj) * 3072;                       \
    _Pragma("unroll")                                                         \
    for (int it = 0; it < 5; ++it) {                                          \
      int u = it * 192 + tid;                                                 \
      if (u < 384) {                                                          \
        int kr = u >> 3, c = u & 7, cs = c ^ (kr & 7);                        \
        gl2lds16(Ks_ + kr * 64 + cs * 8, Lb_ + u * 8);                        \
      } else if (u < 896) {                                                   \
        int v2 = u - 384;                                                     \
        int d = v2 >> 3, c = v2 & 7, cs = c ^ (d & 7);                        \
        long jb = (long)(rj) * 48 + cs * 8;                                   \
        if (jb > 2296) jb = 2296;                                             \
        gl2lds16(Vt + (long)d * 2304 + jb, Lb_ + u * 8);                      \
      } else {                                                                \
        gl2lds16(Kh + (u - 896) * 8, ldsDum + (u - 896) * 8);                 \
      }                                                                       \
    }                                                                         \
  } while (0)

  // QK^T for chunk in buffer KB -> S (rows = 48 keys, cols = 16 queries)
#define AQK(KB, S) do {                                                       \
    const unsigned short* Kt_ = (KB);                                         \
    _Pragma("unroll")                                                         \
    for (int mb = 0; mb < 3; ++mb) { f32x4 z = {0.f,0.f,0.f,0.f}; S[mb] = z; }\
    __builtin_amdgcn_s_setprio(1);                                            \
    _Pragma("unroll")                                                         \
    for (int kk = 0; kk < 2; ++kk) {                                          \
      short8 qf_ = kk ? qf1 : qf0;                                            \
      _Pragma("unroll")                                                       \
      for (int mb = 0; mb < 3; ++mb) {                                        \
        int row = 16 * mb + qi;                                               \
        int c16 = (4 * kk + g) ^ (qi & 7);                                    \
        short8 ka = *(const short8*)(Kt_ + row * 64 + c16 * 8);               \
        S[mb] = mfma16(ka, qf_, S[mb]);                                       \
      }                                                                       \
    }                                                                         \
    __builtin_amdgcn_s_setprio(0);                                            \
  } while (0)

  // softmax (no max-tracking; bounded scores) + PV for chunk with V at VB
#define ASMPV(VB, S) do {                                                     \
    const unsigned short* Vm_ = (VB);                                         \
    unsigned int pw[6];                                                       \
    _Pragma("unroll")                                                         \
    for (int mb = 0; mb < 3; ++mb) {                                          \
      float p0 = __builtin_amdgcn_exp2f(S[mb][0] + msk[mb * 4 + 0]);          \
      float p1 = __builtin_amdgcn_exp2f(S[mb][1] + msk[mb * 4 + 1]);          \
      float p2 = __builtin_amdgcn_exp2f(S[mb][2] + msk[mb * 4 + 2]);          \
      float p3 = __builtin_amdgcn_exp2f(S[mb][3] + msk[mb * 4 + 3]);          \
      lrun += (p0 + p1) + (p2 + p3);                                          \
      pw[2 * mb] = pk2(p0, p1);                                               \
      pw[2 * mb + 1] = pk2(p2, p3);                                           \
    }                                                                         \
    _Pragma("unroll")                                                         \
    for (int mb = 0; mb < 3; ++mb) {                                          \
      u32x2 pv2; pv2.x = pw[2 * mb]; pv2.y = pw[2 * mb + 1];                  \
      *(u32x2*)(&ldsP[wv][qi][16 * mb + 4 * g]) = pv2;                        \
    }                                                                         \
    __builtin_amdgcn_s_setprio(1);                                            \
    _Pragma("unroll")                                                         \
    for (int kk = 0; kk < 2; ++kk) {                                          \
      short8 pb = *(const short8*)(&ldsP[wv][qi][32 * kk + 8 * g]);           \
      _Pragma("unroll")                                                       \
      for (int mb = 0; mb < 4; ++mb) {                                        \
        int row = 16 * mb + qi;                                               \
        int c16 = (4 * kk + g) ^ (qi & 7);                                    \
        short8 va = *(const short8*)(Vm_ + row * 64 + c16 * 8);               \
        cacc[mb] = mfma16(va, pb, cacc[mb]);                                  \
      }                                                                       \
    }                                                                         \
    __builtin_amdgcn_s_setprio(0);                                            \
  } while (0)

  const int rlo = (r > 7) ? r - 7 : 0;
  const int rhi = (r < 40) ? r + 7 : 47;
  const int nch = rhi - rlo + 1;                // 8..15, always >= 2
  f32x4 sE[3], sO[3];                           // even/odd chunk scores
  ASTAGE(0, rlo);
  ASTAGE(1, rlo + 1);
  asm volatile("s_waitcnt vmcnt(5)" ::: "memory");  // stage(0) done
  BARRIER();
  SCHED0();
  AQK(ldsKV, sE);                               // QK(0) from buf 0
  int bc = 0;                                   // t % 3
  for (int t = 0; t < nch; t += 2) {
    const int b1 = (bc + 1 == 3) ? 0 : bc + 1;
    const int b2 = (b1 + 1 == 3) ? 0 : b1 + 1;
    // ---- iter t: QK(t+1) overlaps SM+PV(t) ----
    asm volatile("s_waitcnt vmcnt(0)" ::: "memory");  // stage(t+1) done
    BARRIER();
    SCHED0();
    if (t + 2 < nch) ASTAGE(b2, rlo + t + 2);
    if (t + 1 < nch) AQK(ldsKV + b1 * 7168, sO);
    ASMPV(ldsKV + bc * 7168 + 3072, sE);
    if (t + 1 < nch) {
      // ---- iter t+1: QK(t+2) overlaps SM+PV(t+1) ----
      asm volatile("s_waitcnt vmcnt(0)" ::: "memory");  // stage(t+2) done
      BARRIER();
      SCHED0();
      if (t + 3 < nch) ASTAGE(bc, rlo + t + 3);
      if (t + 2 < nch) AQK(ldsKV + b2 * 7168, sE);
      ASMPV(ldsKV + b1 * 7168 + 3072, sO);
    }
    bc = b2;
  }
#undef ASTAGE
#undef AQK
#undef ASMPV
  // reduce the per-lane denominator across the 4 g-groups, then write ctx
  lrun += __shfl_xor(lrun, 16);
  lrun += __shfl_xor(lrun, 32);
  const float inv = 1.0f / lrun;
  unsigned short* ctx = ws + CTX_E;
  const int b2w = bh >> 3, h2 = bh & 7;
#pragma unroll
  for (int mb = 0; mb < 4; ++mb) {
    u32x2 o;
    o.x = pk2(cacc[mb][0] * inv, cacc[mb][1] * inv);
    o.y = pk2(cacc[mb][2] * inv, cacc[mb][3] * inv);
    long off = ((long)(b2w * 2304 + q)) * 512 + h2 * 64 + 16 * mb + 4 * g;
    *(u32x2*)(ctx + off) = o;
  }
}

// ---------------- launch ----------------
extern "C" void kernel_launch(void* const* d_in, const int* in_sizes, int n_in,
                              void* d_out, int out_size, void* d_ws, size_t ws_size,
                              hipStream_t stream) {
  const float* xq = (const float*)d_in[0];
  const float* xk = (const float*)d_in[1];
  const float* xv = (const float*)d_in[2];
  const float* wq = (const float*)d_in[3];
  const float* bq = (const float*)d_in[4];
  const float* wk = (const float*)d_in[5];
  const float* bk = (const float*)d_in[6];
  const float* wv = (const float*)d_in[7];
  const float* bv = (const float*)d_in[8];
  const float* wo = (const float*)d_in[9];
  const float* bo = (const float*)d_in[10];
  unsigned short* ws = (unsigned short*)d_ws;
  float* out = (float*)d_out;

  proj_qkv_kernel<<<dim3(864), dim3(256), 0, stream>>>(xq, xk, xv, wq, wk, wv,
                                                       bq, bk, bv, ws);
  attn_kernel<<<dim3(768), dim3(192), 0, stream>>>(ws);
  proj_out_kernel<<<dim3(576), dim3(256), 0, stream>>>(ws, wo, bo, out);
}